// Round 5
// baseline (149.003 us; speedup 1.0000x reference)
//
#include <hip/hip_runtime.h>
#include <math.h>

typedef _Float16 half8 __attribute__((ext_vector_type(8)));
typedef float f32x4 __attribute__((ext_vector_type(4)));

// dims
constexpr int B_ = 8;
constexpr int HG = 160, WG = 320;          // guidance spatial
constexpr int H = 80, W = 160;             // x spatial
// ws layout (bytes)
constexpr size_t BWS_OFF  = 0;             // 54 phases * 12288 = 663552
constexpr size_t W1WS_OFF = 663552;        // 9 * 4096 = 36864
constexpr size_t XG_OFF   = 700416;        // 8*80*160*64*2 = 13107200

// swizzled position of (n, kl) within an n x 32kl f16 block:
// paired-n 128B rows, 16B slots XOR-swizzled by (n>>1)&7 -> conflict-free b128 reads.
__device__ __host__ inline int swz_pos(int n, int kl) {
    return ((n >> 1) * 128) + 16 * ((((n & 1) << 2) + (kl >> 3)) ^ ((n >> 1) & 7)) + ((kl & 7) << 1);
}

__device__ inline void gload_lds16(const void* g, void* l) {
    __builtin_amdgcn_global_load_lds(
        (const __attribute__((address_space(1))) void*)g,
        (__attribute__((address_space(3))) void*)l, 16, 0, 0);
}

// ---------------------------------------------------------------------------
// prep: w2 -> Bws phase-blocked: phase p = s*3 + kg (s = K-step of 32, kg =
// 3-k group). Within a 12288B phase block: local col nl = (k%3)*64 + ij,
// swizzled by swz_pos(nl, kl). K = t*64 + cin (step s: t=s>>1, c0=(s&1)*32).
// w1 -> w1ws [s=9][64ch x 32kl] unchanged.   (unchanged from R4)
// ---------------------------------------------------------------------------
__global__ __launch_bounds__(256) void prep(const float* __restrict__ w1,
                                            const float* __restrict__ w2,
                                            char* __restrict__ ws)
{
    int e = blockIdx.x * 256 + threadIdx.x;
    if (e < 18 * 576 * 32) {
        int s = e / (576 * 32), rem = e % (576 * 32);
        int n = rem >> 5, kl = rem & 31;
        int cin = (s & 1) * 32 + kl, t = s >> 1;
        int k = n >> 6, ij = n & 63;
        int kg = k / 3, kap = k - kg * 3;
        int nl = kap * 64 + ij;
        float v = w2[(n * 64 + cin) * 9 + t];
        *(_Float16*)(ws + BWS_OFF + (size_t)(s * 3 + kg) * 12288 + swz_pos(nl, kl)) = (_Float16)v;
    } else {
        int e2 = e - 18 * 576 * 32;
        if (e2 < 9 * 64 * 32) {
            int s = e2 / 2048, rem = e2 % 2048;
            int ch = rem >> 5, kl = rem & 31;
            float v = w1[(ch * 32 + kl) * 9 + s];
            *(_Float16*)(ws + W1WS_OFF + (size_t)s * 4096 + swz_pos(ch, kl)) = (_Float16)v;
        }
    }
}

// ---------------------------------------------------------------------------
// conv1 (3x3 s2 p1, 32->64) + BN + ReLU via MFMA. Output f16 NHWC.
// (unchanged — verified correct since R2)
// ---------------------------------------------------------------------------
__global__ __launch_bounds__(256) void conv1_mfma(
    const float* __restrict__ g, const char* __restrict__ ws_w1,
    const float* __restrict__ gamma, const float* __restrict__ beta,
    const float* __restrict__ mean, const float* __restrict__ var,
    _Float16* __restrict__ xg)
{
    const int tx0 = blockIdx.x * 8, ty0 = blockIdx.y * 8, b = blockIdx.z;
    __shared__ __align__(16) _Float16 gl[17 * 17 * 40];   // 23120 B
    __shared__ __align__(16) _Float16 wlds[64 * 32];      // 4096 B
    const int tid = threadIdx.x;
    const _Float16* w1ws = (const _Float16*)ws_w1;

    for (int idx = tid; idx < 17 * 32 * 17; idx += 256) {
        int rr = idx / (32 * 17); int rem = idx - rr * (32 * 17);
        int cin = rem / 17, cc = rem - cin * 17;
        int gy = 2 * ty0 - 1 + rr, gx = 2 * tx0 - 1 + cc;
        float v = 0.f;
        if (gy >= 0 && gy < HG && gx >= 0 && gx < WG)
            v = g[((size_t)(b * 32 + cin) * HG + gy) * WG + gx];
        gl[(rr * 17 + cc) * 40 + cin] = (_Float16)v;
    }

    const int lane = tid & 63, wid = tid >> 6;
    const int wm = wid & 1, wn = wid >> 1;
    const int c = lane & 15, grp = lane >> 4;
    const int slot = ((((c & 1) << 2) + grp) ^ ((c >> 1) & 7));
    const int bbase = wn * 1024 + (c >> 1) * 64 + slot * 8;   // f16 units

    f32x4 zf = {0.f, 0.f, 0.f, 0.f};
    f32x4 acc[2][2];
    acc[0][0] = zf; acc[0][1] = zf; acc[1][0] = zf; acc[1][1] = zf;

    half8 stg = *(const half8*)(w1ws + tid * 8);   // step 0 prefetch

#pragma unroll
    for (int s = 0; s < 9; ++s) {
        __syncthreads();
        *(half8*)&wlds[tid * 8] = stg;
        __syncthreads();
        if (s < 8) stg = *(const half8*)(w1ws + (s + 1) * 2048 + tid * 8);
        const int dy = s / 3, dx = s - dy * 3;
        half8 af[2];
#pragma unroll
        for (int mt = 0; mt < 2; ++mt) {
            int rr = 2 * (wm * 4 + mt * 2 + (c >> 3)) + dy;
            int cc2 = 2 * (c & 7) + dx;
            af[mt] = *(const half8*)&gl[(rr * 17 + cc2) * 40 + grp * 8];
        }
#pragma unroll
        for (int nt = 0; nt < 2; ++nt) {
            half8 bf = *(const half8*)&wlds[nt * 512 + bbase];
            acc[0][nt] = __builtin_amdgcn_mfma_f32_16x16x32_f16(af[0], bf, acc[0][nt], 0, 0, 0);
            acc[1][nt] = __builtin_amdgcn_mfma_f32_16x16x32_f16(af[1], bf, acc[1][nt], 0, 0, 0);
        }
    }

#pragma unroll
    for (int nt = 0; nt < 2; ++nt) {
        int ch = wn * 32 + nt * 16 + c;
        float mu = mean[ch], scv = rsqrtf(var[ch] + 1e-5f) * gamma[ch], bt = beta[ch];
#pragma unroll
        for (int mt = 0; mt < 2; ++mt) {
#pragma unroll
            for (int r = 0; r < 4; ++r) {
                int p = wm * 32 + mt * 16 + grp * 4 + r;
                int y = ty0 + (p >> 3), xc = tx0 + (p & 7);
                float v = (acc[mt][nt][r] - mu) * scv + bt;
                v = fmaxf(v, 0.f);
                xg[(((size_t)(b * H + y) * W + xc) << 6) + ch] = (_Float16)v;
            }
        }
    }
}

// ---------------------------------------------------------------------------
// conv2 (3x3 s1 p1, 64->576) + softmax(9) + convex combine + pixel shuffle.
// 512 thr = 8 waves: ng = wid&3 (16-ij set, k-complete per lane), mg = wid>>2.
// Tile 16x8 = 128 px. Weight stream: 54 phases of 12288 B, ring of 8 slots,
// issued 6 ahead by 6 loader waves (2 x 1024B dwordx4-LDS chunks each),
// s_waitcnt vmcnt(8) + raw s_barrier per phase (never drains to 0 in-loop).
// ---------------------------------------------------------------------------
__global__ __launch_bounds__(512, 2) void conv2_mfma(
    const _Float16* __restrict__ xg, const char* __restrict__ ws_b,
    const float* __restrict__ disp, float* __restrict__ out)
{
    const int tx0 = blockIdx.x * 16, ty0 = blockIdx.y * 8, b = blockIdx.z;
    __shared__ __align__(16) _Float16 xs[180 * 64];       // 23040 B, XOR-swizzled
    __shared__ __align__(16) _Float16 ring[8 * 6144];     // 98304 B (8 x 12288)
    __shared__ __align__(16) _Float16 trash[512];         // 1024 B dummy-DMA sink
    __shared__ float d8s[180];
    const int tid = threadIdx.x;
    const int lane = tid & 63, wid = tid >> 6;

    // stage x window 10x18x64 f16, swizzled: 16B slot' = slot ^ (wp&7)
    half8 zero8;
#pragma unroll
    for (int j = 0; j < 8; ++j) zero8[j] = (_Float16)0.f;
    for (int cidx = tid; cidx < 1440; cidx += 512) {
        int wp = cidx >> 3, slot = cidx & 7;
        int rr = wp / 18, cc = wp - rr * 18;
        int y = ty0 - 1 + rr, xc = tx0 - 1 + cc;
        half8 v = zero8;
        if (y >= 0 && y < H && xc >= 0 && xc < W)
            v = *(const half8*)(xg + (((size_t)(b * H + y) * W + xc) << 6) + slot * 8);
        int slotp = slot ^ (wp & 7);
        *(half8*)&xs[wp * 64 + slotp * 8] = v;
    }
    if (tid < 180) {
        int rr = tid / 18, cc = tid - rr * 18;
        int y = ty0 - 1 + rr, xc = tx0 - 1 + cc;
        float v = 0.f;
        if (y >= 0 && y < H && xc >= 0 && xc < W) v = 8.f * disp[(b * H + y) * W + xc];
        d8s[tid] = v;
    }

    const bool loader = (wid < 6);
    const int myoff = wid * 2048 + lane * 16;   // loader's byte offset in a phase

    // prologue: issue phases 0..5 (6 deep)
    if (loader) {
#pragma unroll
        for (int q = 0; q < 6; ++q) {
            const char* src = ws_b + (size_t)q * 12288 + myoff;
            char* dst = (char*)ring + q * 12288 + myoff;
            gload_lds16(src, dst);
            gload_lds16(src + 1024, dst + 1024);
        }
    }

    const int ng = wid & 3, mg = wid >> 2;
    const int c = lane & 15, grp = lane >> 4;
    const int slot_b = ((((c & 1) << 2) + grp) ^ ((c >> 1) & 7));
    const int bbase = ng * 512 + (c >> 1) * 64 + slot_b * 8;   // f16 units

    f32x4 zf = {0.f, 0.f, 0.f, 0.f};
    f32x4 acc[4][9];
#pragma unroll
    for (int m = 0; m < 4; ++m)
#pragma unroll
        for (int k = 0; k < 9; ++k) acc[m][k] = zf;

    __syncthreads();   // xs, d8s ready (prologue DMA may or may not be drained
                       // here; the counted waits below are correct either way)

    for (int s = 0; s < 18; ++s) {
        const int t = s >> 1;
        const int dy = t / 3, dx = t - dy * 3;
        const int aslot = (s & 1) * 4 + grp;
#pragma unroll
        for (int kg = 0; kg < 3; ++kg) {
            const int p = s * 3 + kg;
            // issue DMA for phase p+6 (slot (p+6)&7 last read at phase p-2,
            // ordered before barrier(p-1) which we already passed)
            if (loader) {
                if (p < 48) {
                    const char* src = ws_b + (size_t)(p + 6) * 12288 + myoff;
                    char* dst = (char*)ring + ((p + 6) & 7) * 12288 + myoff;
                    gload_lds16(src, dst);
                    gload_lds16(src + 1024, dst + 1024);
                } else {
                    // dummy issues keep per-wave vmcnt accounting uniform
                    gload_lds16(ws_b + myoff, (char*)trash + (lane << 4));
                    gload_lds16(ws_b + myoff, (char*)trash + (lane << 4));
                }
            }
            // A-fragments from xs (read-only): issue before the wait so the
            // ds_read latency overlaps it. Re-read each phase (memory clobber
            // below forbids CSE) -> af not live across the issue window.
            half8 af[4];
#pragma unroll
            for (int mt = 0; mt < 4; ++mt) {
                int wp = (mg * 4 + mt + dy) * 18 + c + dx;
                af[mt] = *(const half8*)&xs[wp * 64 + (aslot ^ (wp & 7)) * 8];
            }
            // wait: keep >=2-phase margin (drains through phase p+2's chunks;
            // tolerant of a few stray vmem ops if any)
            asm volatile("s_waitcnt vmcnt(8)" ::: "memory");
            __builtin_amdgcn_s_barrier();
            __builtin_amdgcn_sched_barrier(0);
            const _Float16* wb = ring + (p & 7) * 6144;
            __builtin_amdgcn_s_setprio(1);
#pragma unroll
            for (int kap = 0; kap < 3; ++kap) {
                half8 bf = *(const half8*)(wb + kap * 2048 + bbase);
#pragma unroll
                for (int mt = 0; mt < 4; ++mt)
                    acc[mt][kg * 3 + kap] = __builtin_amdgcn_mfma_f32_16x16x32_f16(
                        af[mt], bf, acc[mt][kg * 3 + kap], 0, 0, 0);
            }
            __builtin_amdgcn_s_setprio(0);
        }
    }

    // epilogue: lane-local softmax over 9 k per (pixel, ij)
    const int ij = ng * 16 + c;
    const int oi = ij >> 3, oj = ij & 7;
#pragma unroll
    for (int mt = 0; mt < 4; ++mt) {
#pragma unroll
        for (int r = 0; r < 4; ++r) {
            int pr = mg * 4 + mt, pc = grp * 4 + r;
            float pat[9];
#pragma unroll
            for (int k9 = 0; k9 < 9; ++k9) pat[k9] = d8s[(pr + k9 / 3) * 18 + pc + k9 % 3];
            float mx = acc[mt][0][r];
#pragma unroll
            for (int k9 = 1; k9 < 9; ++k9) mx = fmaxf(mx, acc[mt][k9][r]);
            float sum = 0.f, up = 0.f;
#pragma unroll
            for (int k9 = 0; k9 < 9; ++k9) {
                float e = __expf(acc[mt][k9][r] - mx);
                sum += e; up += e * pat[k9];
            }
            int y = ty0 + pr, xc = tx0 + pc;
            out[((size_t)(b * (8 * H) + y * 8 + oi)) * (size_t)(8 * W) + xc * 8 + oj] = up / sum;
        }
    }
}

// ---------------------------------------------------------------------------
extern "C" void kernel_launch(void* const* d_in, const int* in_sizes, int n_in,
                              void* d_out, int out_size, void* d_ws, size_t ws_size,
                              hipStream_t stream)
{
    const float* guidance = (const float*)d_in[0];
    const float* disp     = (const float*)d_in[1];
    const float* conv1_w  = (const float*)d_in[2];
    const float* bn_gamma = (const float*)d_in[3];
    const float* bn_beta  = (const float*)d_in[4];
    const float* bn_mean  = (const float*)d_in[5];
    const float* bn_var   = (const float*)d_in[6];
    const float* conv2_w  = (const float*)d_in[7];
    float* out = (float*)d_out;
    char* ws = (char*)d_ws;
    _Float16* xg = (_Float16*)(ws + XG_OFF);

    prep<<<dim3((18 * 576 * 32 + 9 * 64 * 32 + 255) / 256), dim3(256), 0, stream>>>(
        conv1_w, conv2_w, ws);
    dim3 grid1(W / 8, H / 8, B_);    // (20, 10, 8)
    conv1_mfma<<<grid1, dim3(256), 0, stream>>>(
        guidance, ws + W1WS_OFF, bn_gamma, bn_beta, bn_mean, bn_var, xg);
    dim3 grid2(W / 16, H / 8, B_);   // (10, 10, 8)
    conv2_mfma<<<grid2, dim3(512), 0, stream>>>(
        xg, ws + BWS_OFF, disp, out);
}

// Round 6
// 140.727 us; speedup vs baseline: 1.0588x; 1.0588x over previous
//
#include <hip/hip_runtime.h>
#include <math.h>

typedef _Float16 half8 __attribute__((ext_vector_type(8)));
typedef float f32x4 __attribute__((ext_vector_type(4)));

// dims
constexpr int B_ = 8;
constexpr int HG = 160, WG = 320;          // guidance spatial
constexpr int H = 80, W = 160;             // x spatial
// ws layout (bytes)
constexpr size_t CWS_OFF  = 0;             // 54 phases * 4 ng * 3072 = 663552
constexpr size_t W1WS_OFF = 663552;        // 9 * 4096 = 36864
constexpr size_t XG_OFF   = 700416;        // 8*80*160*64*2 = 13107200

// swizzled position of (n, kl) within a 16n x 32kl f16 fragment block (1024B):
// paired-n 128B rows, 16B slots XOR-swizzled by (n>>1)&7 -> conflict-free b128.
__device__ __host__ inline int swz_pos(int n, int kl) {
    return ((n >> 1) * 128) + 16 * ((((n & 1) << 2) + (kl >> 3)) ^ ((n >> 1) & 7)) + ((kl & 7) << 1);
}

__device__ inline void gload_lds16(const void* g, void* l) {
    __builtin_amdgcn_global_load_lds(
        (const __attribute__((address_space(1))) void*)g,
        (__attribute__((address_space(3))) void*)l, 16, 0, 0);
}

// ---------------------------------------------------------------------------
// prep: w2 -> Cws [54 phases][4 ng][3072 B]. Phase p = s*3 + kg covers k in
// [kg*3, kg*3+3) at K-step s (K = t*64 + cin; t = s>>1, c0 = (s&1)*32).
// Within a (p, ng) 3072B block: kap in [0,3) x 1024B fragment, element
// (nl16 = ij&15, kl) at swz_pos. Each wave DMAs its (p, ng=wid) block
// LINEARLY; the swizzle is baked in here (rule: pre-permute source).
// w1 -> w1ws [s=9][64ch x 32kl] unchanged.
// ---------------------------------------------------------------------------
__global__ __launch_bounds__(256) void prep(const float* __restrict__ w1,
                                            const float* __restrict__ w2,
                                            char* __restrict__ ws)
{
    int e = blockIdx.x * 256 + threadIdx.x;
    if (e < 18 * 576 * 32) {
        int s = e / (576 * 32), rem = e % (576 * 32);
        int n = rem >> 5, kl = rem & 31;
        int cin = (s & 1) * 32 + kl, t = s >> 1;
        int k = n >> 6, ij = n & 63;
        int kg = k / 3, kap = k - kg * 3;
        int ng = ij >> 4, nl16 = ij & 15;
        int p = s * 3 + kg;
        float v = w2[(n * 64 + cin) * 9 + t];
        *(_Float16*)(ws + CWS_OFF + (size_t)(p * 4 + ng) * 3072 + kap * 1024
                     + swz_pos(nl16, kl)) = (_Float16)v;
    } else {
        int e2 = e - 18 * 576 * 32;
        if (e2 < 9 * 64 * 32) {
            int s = e2 / 2048, rem = e2 % 2048;
            int ch = rem >> 5, kl = rem & 31;
            float v = w1[(ch * 32 + kl) * 9 + s];
            *(_Float16*)(ws + W1WS_OFF + (size_t)s * 4096 + swz_pos(ch, kl)) = (_Float16)v;
        }
    }
}

// ---------------------------------------------------------------------------
// conv1 (3x3 s2 p1, 32->64) + BN + ReLU via MFMA. Output f16 NHWC.
// (unchanged — verified correct since R2)
// ---------------------------------------------------------------------------
__global__ __launch_bounds__(256) void conv1_mfma(
    const float* __restrict__ g, const char* __restrict__ ws_w1,
    const float* __restrict__ gamma, const float* __restrict__ beta,
    const float* __restrict__ mean, const float* __restrict__ var,
    _Float16* __restrict__ xg)
{
    const int tx0 = blockIdx.x * 8, ty0 = blockIdx.y * 8, b = blockIdx.z;
    __shared__ __align__(16) _Float16 gl[17 * 17 * 40];   // 23120 B
    __shared__ __align__(16) _Float16 wlds[64 * 32];      // 4096 B
    const int tid = threadIdx.x;
    const _Float16* w1ws = (const _Float16*)ws_w1;

    for (int idx = tid; idx < 17 * 32 * 17; idx += 256) {
        int rr = idx / (32 * 17); int rem = idx - rr * (32 * 17);
        int cin = rem / 17, cc = rem - cin * 17;
        int gy = 2 * ty0 - 1 + rr, gx = 2 * tx0 - 1 + cc;
        float v = 0.f;
        if (gy >= 0 && gy < HG && gx >= 0 && gx < WG)
            v = g[((size_t)(b * 32 + cin) * HG + gy) * WG + gx];
        gl[(rr * 17 + cc) * 40 + cin] = (_Float16)v;
    }

    const int lane = tid & 63, wid = tid >> 6;
    const int wm = wid & 1, wn = wid >> 1;
    const int c = lane & 15, grp = lane >> 4;
    const int slot = ((((c & 1) << 2) + grp) ^ ((c >> 1) & 7));
    const int bbase = wn * 1024 + (c >> 1) * 64 + slot * 8;   // f16 units

    f32x4 zf = {0.f, 0.f, 0.f, 0.f};
    f32x4 acc[2][2];
    acc[0][0] = zf; acc[0][1] = zf; acc[1][0] = zf; acc[1][1] = zf;

    half8 stg = *(const half8*)(w1ws + tid * 8);   // step 0 prefetch

#pragma unroll
    for (int s = 0; s < 9; ++s) {
        __syncthreads();
        *(half8*)&wlds[tid * 8] = stg;
        __syncthreads();
        if (s < 8) stg = *(const half8*)(w1ws + (s + 1) * 2048 + tid * 8);
        const int dy = s / 3, dx = s - dy * 3;
        half8 af[2];
#pragma unroll
        for (int mt = 0; mt < 2; ++mt) {
            int rr = 2 * (wm * 4 + mt * 2 + (c >> 3)) + dy;
            int cc2 = 2 * (c & 7) + dx;
            af[mt] = *(const half8*)&gl[(rr * 17 + cc2) * 40 + grp * 8];
        }
#pragma unroll
        for (int nt = 0; nt < 2; ++nt) {
            half8 bf = *(const half8*)&wlds[nt * 512 + bbase];
            acc[0][nt] = __builtin_amdgcn_mfma_f32_16x16x32_f16(af[0], bf, acc[0][nt], 0, 0, 0);
            acc[1][nt] = __builtin_amdgcn_mfma_f32_16x16x32_f16(af[1], bf, acc[1][nt], 0, 0, 0);
        }
    }

#pragma unroll
    for (int nt = 0; nt < 2; ++nt) {
        int ch = wn * 32 + nt * 16 + c;
        float mu = mean[ch], scv = rsqrtf(var[ch] + 1e-5f) * gamma[ch], bt = beta[ch];
#pragma unroll
        for (int mt = 0; mt < 2; ++mt) {
#pragma unroll
            for (int r = 0; r < 4; ++r) {
                int p = wm * 32 + mt * 16 + grp * 4 + r;
                int y = ty0 + (p >> 3), xc = tx0 + (p & 7);
                float v = (acc[mt][nt][r] - mu) * scv + bt;
                v = fmaxf(v, 0.f);
                xg[(((size_t)(b * H + y) * W + xc) << 6) + ch] = (_Float16)v;
            }
        }
    }
}

// ---------------------------------------------------------------------------
// conv2 (3x3 s1 p1, 64->576) + softmax(9) + convex combine + pixel shuffle.
// BARRIER-FREE K-loop: 256 thr = 4 waves, wave w = ng (its 16-ij set,
// k-complete per lane -> lane-local softmax), each wave covers ALL 64 px
// (16x4 tile, Mt=4). Per-wave PRIVATE LDS B-ring (4 slots x 3072B) filled by
// its own global_load_lds (contiguous linear copy of the pre-swizzled Cws
// block) and guarded only by its own counted s_waitcnt vmcnt(6). No
// __syncthreads after staging; 2 independent blocks/CU.
// ---------------------------------------------------------------------------
__global__ __launch_bounds__(256, 2) void conv2_mfma(
    const _Float16* __restrict__ xg, const char* __restrict__ ws_c,
    const float* __restrict__ disp, float* __restrict__ out)
{
    const int tx0 = blockIdx.x * 16, ty0 = blockIdx.y * 4, b = blockIdx.z;
    __shared__ __align__(16) _Float16 xs[108 * 64];        // 6r x 18c x 64ch, 13824 B
    __shared__ __align__(16) _Float16 ring[4][4][1536];    // [wave][slot], 49152 B
    __shared__ __align__(16) _Float16 trash[512];          // 1024 B dummy sink
    __shared__ float d8s[108];
    const int tid = threadIdx.x;
    const int lane = tid & 63, wid = tid >> 6;

    // stage x window 6x18x64 f16, swizzled: 16B slot' = slot ^ (wp&7)
    half8 zero8;
#pragma unroll
    for (int j = 0; j < 8; ++j) zero8[j] = (_Float16)0.f;
    for (int cidx = tid; cidx < 864; cidx += 256) {
        int wp = cidx >> 3, slot = cidx & 7;
        int rr = wp / 18, cc = wp - rr * 18;
        int y = ty0 - 1 + rr, xc = tx0 - 1 + cc;
        half8 v = zero8;
        if (y >= 0 && y < H && xc >= 0 && xc < W)
            v = *(const half8*)(xg + (((size_t)(b * H + y) * W + xc) << 6) + slot * 8);
        *(half8*)&xs[wp * 64 + (slot ^ (wp & 7)) * 8] = v;
    }
    if (tid < 108) {
        int rr = tid / 18, cc = tid - rr * 18;
        int y = ty0 - 1 + rr, xc = tx0 - 1 + cc;
        float v = 0.f;
        if (y >= 0 && y < H && xc >= 0 && xc < W) v = 8.f * disp[(b * H + y) * W + xc];
        d8s[tid] = v;
    }

    const int c = lane & 15, grp = lane >> 4;
    const int slot_b = ((((c & 1) << 2) + grp) ^ ((c >> 1) & 7));
    const int lbase = (c >> 1) * 64 + slot_b * 8;          // f16 units, in 512-f16 frag
    _Float16* wring = &ring[wid][0][0];                    // this wave's ring base
    const char* csrc = ws_c + (size_t)wid * 3072;          // this wave's ng slice

    f32x4 zf = {0.f, 0.f, 0.f, 0.f};
    f32x4 acc[4][9];
#pragma unroll
    for (int m = 0; m < 4; ++m)
#pragma unroll
        for (int k = 0; k < 9; ++k) acc[m][k] = zf;

    __syncthreads();   // xs, d8s ready; all staging loads drained (vmcnt->0)

    // per-wave DMA of one phase block (3072 B, linear; swizzle baked in Cws)
    auto issue = [&](int p) {
        const char* s = csrc + (size_t)p * 12288 + lane * 16;
        char* d = (char*)wring + (p & 3) * 3072 + lane * 16;
        gload_lds16(s, d);
        gload_lds16(s + 1024, d + 1024);
        gload_lds16(s + 2048, d + 2048);
    };

    // prologue: 3 phases in flight
    issue(0); issue(1); issue(2);

    for (int s = 0; s < 18; ++s) {
        const int t = s >> 1;
        const int dy = t / 3, dx = t - dy * 3;
        const int aslot = (s & 1) * 4 + grp;
        half8 af[4];   // read once per K-step, held across the 3 phases
#pragma unroll
        for (int mt = 0; mt < 4; ++mt) {
            int wp = (mt + dy) * 18 + c + dx;
            af[mt] = *(const half8*)&xs[wp * 64 + (aslot ^ (wp & 7)) * 8];
        }
#pragma unroll
        for (int kg = 0; kg < 3; ++kg) {
            const int p = s * 3 + kg;
            if (p < 51) {
                issue(p + 3);
            } else {   // dummies keep per-wave vmcnt accounting uniform
                gload_lds16(ws_c + lane * 16, (char*)trash + lane * 16);
                gload_lds16(ws_c + lane * 16, (char*)trash + lane * 16);
                gload_lds16(ws_c + lane * 16, (char*)trash + lane * 16);
            }
            // own-wave wait: <=6 outstanding => phases <= p+1 complete.
            // margin 3 below the exact bound (9) tolerates stray vmem ops.
            asm volatile("s_waitcnt vmcnt(6)" ::: "memory");
            __builtin_amdgcn_sched_barrier(0);
            const _Float16* wb = wring + (p & 3) * 1536;
            __builtin_amdgcn_s_setprio(1);
#pragma unroll
            for (int kap = 0; kap < 3; ++kap) {
                half8 bf = *(const half8*)(wb + kap * 512 + lbase);
#pragma unroll
                for (int mt = 0; mt < 4; ++mt)
                    acc[mt][kg * 3 + kap] = __builtin_amdgcn_mfma_f32_16x16x32_f16(
                        af[mt], bf, acc[mt][kg * 3 + kap], 0, 0, 0);
            }
            __builtin_amdgcn_s_setprio(0);
        }
    }

    // epilogue: lane-local softmax over 9 k per (pixel, ij); no barrier needed
    const int ij = wid * 16 + c;
    const int oi = ij >> 3, oj = ij & 7;
#pragma unroll
    for (int mt = 0; mt < 4; ++mt) {
#pragma unroll
        for (int r = 0; r < 4; ++r) {
            int pr = mt, pc = grp * 4 + r;
            float pat[9];
#pragma unroll
            for (int k9 = 0; k9 < 9; ++k9) pat[k9] = d8s[(pr + k9 / 3) * 18 + pc + k9 % 3];
            float mx = acc[mt][0][r];
#pragma unroll
            for (int k9 = 1; k9 < 9; ++k9) mx = fmaxf(mx, acc[mt][k9][r]);
            float sum = 0.f, up = 0.f;
#pragma unroll
            for (int k9 = 0; k9 < 9; ++k9) {
                float e = __expf(acc[mt][k9][r] - mx);
                sum += e; up += e * pat[k9];
            }
            int y = ty0 + pr, xc = tx0 + pc;
            out[((size_t)(b * (8 * H) + y * 8 + oi)) * (size_t)(8 * W) + xc * 8 + oj] = up / sum;
        }
    }
}

// ---------------------------------------------------------------------------
extern "C" void kernel_launch(void* const* d_in, const int* in_sizes, int n_in,
                              void* d_out, int out_size, void* d_ws, size_t ws_size,
                              hipStream_t stream)
{
    const float* guidance = (const float*)d_in[0];
    const float* disp     = (const float*)d_in[1];
    const float* conv1_w  = (const float*)d_in[2];
    const float* bn_gamma = (const float*)d_in[3];
    const float* bn_beta  = (const float*)d_in[4];
    const float* bn_mean  = (const float*)d_in[5];
    const float* bn_var   = (const float*)d_in[6];
    const float* conv2_w  = (const float*)d_in[7];
    float* out = (float*)d_out;
    char* ws = (char*)d_ws;
    _Float16* xg = (_Float16*)(ws + XG_OFF);

    prep<<<dim3((18 * 576 * 32 + 9 * 64 * 32 + 255) / 256), dim3(256), 0, stream>>>(
        conv1_w, conv2_w, ws);
    dim3 grid1(W / 8, H / 8, B_);    // (20, 10, 8)
    conv1_mfma<<<grid1, dim3(256), 0, stream>>>(
        guidance, ws + W1WS_OFF, bn_gamma, bn_beta, bn_mean, bn_var, xg);
    dim3 grid2(W / 16, H / 4, B_);   // (10, 20, 8)
    conv2_mfma<<<grid2, dim3(256), 0, stream>>>(
        xg, ws + CWS_OFF, disp, out);
}

// Round 7
// 124.993 us; speedup vs baseline: 1.1921x; 1.1259x over previous
//
#include <hip/hip_runtime.h>
#include <math.h>

typedef _Float16 half8 __attribute__((ext_vector_type(8)));
typedef float f32x4 __attribute__((ext_vector_type(4)));

// dims
constexpr int B_ = 8;
constexpr int HG = 160, WG = 320;          // guidance spatial
constexpr int H = 80, W = 160;             // x spatial
// ws layout (bytes)
constexpr size_t CWS_OFF  = 0;             // 4 ng * 165888 = 663552
constexpr size_t W1WS_OFF = 663552;        // 9 * 4096 = 36864
constexpr size_t XG_OFF   = 700416;        // 8*80*160*64*2 = 13107200

// swizzled position of (n, kl) within a 16n x 32kl f16 fragment block (1024B):
// paired-n 128B rows, 16B slots XOR-swizzled by (n>>1)&7 -> conflict-free b128.
// (still used for conv1's weight staging)
__device__ __host__ inline int swz_pos(int n, int kl) {
    return ((n >> 1) * 128) + 16 * ((((n & 1) << 2) + (kl >> 3)) ^ ((n >> 1) & 7)) + ((kl & 7) << 1);
}

// ---------------------------------------------------------------------------
// prep: w2 -> Cws register-direct streams [ng][18 s][9 k][1024B fragment].
// Fragment byte layout = MFMA B-operand register image: lane l (l = grp*16+n,
// grp = kl>>3, n = ij&15) holds bytes [l*16, l*16+16) = w2 elements
// kl = grp*8..grp*8+7 at 2B each. K = t*64 + cin; s = t*2 + (cin>>5),
// kl = cin&31. n_global = k*64 + ng*16 + n.
// w1 -> w1ws [s=9][64ch x 32kl swizzled] unchanged (conv1).
// ---------------------------------------------------------------------------
__global__ __launch_bounds__(256) void prep(const float* __restrict__ w1,
                                            const float* __restrict__ w2,
                                            char* __restrict__ ws)
{
    int e = blockIdx.x * 256 + threadIdx.x;
    if (e < 18 * 576 * 32) {
        int s = e / (576 * 32), rem = e % (576 * 32);
        int n = rem >> 5, kl = rem & 31;
        int cin = (s & 1) * 32 + kl, t = s >> 1;
        int k = n >> 6, ij = n & 63;
        int ng = ij >> 4, nl16 = ij & 15;
        float v = w2[(n * 64 + cin) * 9 + t];
        size_t off = (size_t)ng * 165888 + (size_t)(s * 9 + k) * 1024
                   + ((kl >> 3) * 16 + nl16) * 16 + (kl & 7) * 2;
        *(_Float16*)(ws + CWS_OFF + off) = (_Float16)v;
    } else {
        int e2 = e - 18 * 576 * 32;
        if (e2 < 9 * 64 * 32) {
            int s = e2 / 2048, rem = e2 % 2048;
            int ch = rem >> 5, kl = rem & 31;
            float v = w1[(ch * 32 + kl) * 9 + s];
            *(_Float16*)(ws + W1WS_OFF + (size_t)s * 4096 + swz_pos(ch, kl)) = (_Float16)v;
        }
    }
}

// ---------------------------------------------------------------------------
// conv1 (3x3 s2 p1, 32->64) + BN + ReLU via MFMA. Output f16 NHWC.
// (unchanged — verified correct since R2)
// ---------------------------------------------------------------------------
__global__ __launch_bounds__(256) void conv1_mfma(
    const float* __restrict__ g, const char* __restrict__ ws_w1,
    const float* __restrict__ gamma, const float* __restrict__ beta,
    const float* __restrict__ mean, const float* __restrict__ var,
    _Float16* __restrict__ xg)
{
    const int tx0 = blockIdx.x * 8, ty0 = blockIdx.y * 8, b = blockIdx.z;
    __shared__ __align__(16) _Float16 gl[17 * 17 * 40];   // 23120 B
    __shared__ __align__(16) _Float16 wlds[64 * 32];      // 4096 B
    const int tid = threadIdx.x;
    const _Float16* w1ws = (const _Float16*)ws_w1;

    for (int idx = tid; idx < 17 * 32 * 17; idx += 256) {
        int rr = idx / (32 * 17); int rem = idx - rr * (32 * 17);
        int cin = rem / 17, cc = rem - cin * 17;
        int gy = 2 * ty0 - 1 + rr, gx = 2 * tx0 - 1 + cc;
        float v = 0.f;
        if (gy >= 0 && gy < HG && gx >= 0 && gx < WG)
            v = g[((size_t)(b * 32 + cin) * HG + gy) * WG + gx];
        gl[(rr * 17 + cc) * 40 + cin] = (_Float16)v;
    }

    const int lane = tid & 63, wid = tid >> 6;
    const int wm = wid & 1, wn = wid >> 1;
    const int c = lane & 15, grp = lane >> 4;
    const int slot = ((((c & 1) << 2) + grp) ^ ((c >> 1) & 7));
    const int bbase = wn * 1024 + (c >> 1) * 64 + slot * 8;   // f16 units

    f32x4 zf = {0.f, 0.f, 0.f, 0.f};
    f32x4 acc[2][2];
    acc[0][0] = zf; acc[0][1] = zf; acc[1][0] = zf; acc[1][1] = zf;

    half8 stg = *(const half8*)(w1ws + tid * 8);   // step 0 prefetch

#pragma unroll
    for (int s = 0; s < 9; ++s) {
        __syncthreads();
        *(half8*)&wlds[tid * 8] = stg;
        __syncthreads();
        if (s < 8) stg = *(const half8*)(w1ws + (s + 1) * 2048 + tid * 8);
        const int dy = s / 3, dx = s - dy * 3;
        half8 af[2];
#pragma unroll
        for (int mt = 0; mt < 2; ++mt) {
            int rr = 2 * (wm * 4 + mt * 2 + (c >> 3)) + dy;
            int cc2 = 2 * (c & 7) + dx;
            af[mt] = *(const half8*)&gl[(rr * 17 + cc2) * 40 + grp * 8];
        }
#pragma unroll
        for (int nt = 0; nt < 2; ++nt) {
            half8 bf = *(const half8*)&wlds[nt * 512 + bbase];
            acc[0][nt] = __builtin_amdgcn_mfma_f32_16x16x32_f16(af[0], bf, acc[0][nt], 0, 0, 0);
            acc[1][nt] = __builtin_amdgcn_mfma_f32_16x16x32_f16(af[1], bf, acc[1][nt], 0, 0, 0);
        }
    }

#pragma unroll
    for (int nt = 0; nt < 2; ++nt) {
        int ch = wn * 32 + nt * 16 + c;
        float mu = mean[ch], scv = rsqrtf(var[ch] + 1e-5f) * gamma[ch], bt = beta[ch];
#pragma unroll
        for (int mt = 0; mt < 2; ++mt) {
#pragma unroll
            for (int r = 0; r < 4; ++r) {
                int p = wm * 32 + mt * 16 + grp * 4 + r;
                int y = ty0 + (p >> 3), xc = tx0 + (p & 7);
                float v = (acc[mt][nt][r] - mu) * scv + bt;
                v = fmaxf(v, 0.f);
                xg[(((size_t)(b * H + y) * W + xc) << 6) + ch] = (_Float16)v;
            }
        }
    }
}

// ---------------------------------------------------------------------------
// conv2 (3x3 s1 p1, 64->576) + softmax(9) + convex combine + pixel shuffle.
// REGISTER-DIRECT B: 256 thr = 4 waves, wave w = ng (16-ij set, k-complete
// per lane -> lane-local softmax), 16x4 px tile, Mt=4. Each wave streams its
// weight fragments straight from L2 into VGPRs (9 coalesced dwordx4 loads
// per K-step, software-pipelined one step ahead). NO LDS for B, NO barriers
// in the K-loop, no manual waitcnt — compiler-scheduled register loads.
// LDS holds only the x window (XOR-swizzled) + disp tile.
// ---------------------------------------------------------------------------
__global__ __launch_bounds__(256, 2) void conv2_mfma(
    const _Float16* __restrict__ xg, const char* __restrict__ ws_c,
    const float* __restrict__ disp, float* __restrict__ out)
{
    const int tx0 = blockIdx.x * 16, ty0 = blockIdx.y * 4, b = blockIdx.z;
    __shared__ __align__(16) _Float16 xs[108 * 64];        // 6r x 18c x 64ch, 13824 B
    __shared__ float d8s[108];
    const int tid = threadIdx.x;
    const int lane = tid & 63, wid = tid >> 6;

    // stage x window 6x18x64 f16, swizzled: 16B slot' = slot ^ (wp&7)
    half8 zero8;
#pragma unroll
    for (int j = 0; j < 8; ++j) zero8[j] = (_Float16)0.f;
    for (int cidx = tid; cidx < 864; cidx += 256) {
        int wp = cidx >> 3, slot = cidx & 7;
        int rr = wp / 18, cc = wp - rr * 18;
        int y = ty0 - 1 + rr, xc = tx0 - 1 + cc;
        half8 v = zero8;
        if (y >= 0 && y < H && xc >= 0 && xc < W)
            v = *(const half8*)(xg + (((size_t)(b * H + y) * W + xc) << 6) + slot * 8);
        *(half8*)&xs[wp * 64 + (slot ^ (wp & 7)) * 8] = v;
    }
    if (tid < 108) {
        int rr = tid / 18, cc = tid - rr * 18;
        int y = ty0 - 1 + rr, xc = tx0 - 1 + cc;
        float v = 0.f;
        if (y >= 0 && y < H && xc >= 0 && xc < W) v = 8.f * disp[(b * H + y) * W + xc];
        d8s[tid] = v;
    }

    const int c = lane & 15, grp = lane >> 4;

    f32x4 zf = {0.f, 0.f, 0.f, 0.f};
    f32x4 acc[4][9];
#pragma unroll
    for (int m = 0; m < 4; ++m)
#pragma unroll
        for (int k = 0; k < 9; ++k) acc[m][k] = zf;

    // this wave's weight stream: [18 s][9 k][1024B], lane slice = lane*16 B
    const _Float16* wp = (const _Float16*)ws_c + (size_t)wid * 82944 + lane * 8;

    // prefetch step 0 fragments into registers
    half8 bf[9];
#pragma unroll
    for (int k = 0; k < 9; ++k) bf[k] = *(const half8*)(wp + k * 512);

    __syncthreads();   // xs, d8s ready

#pragma unroll 2
    for (int s = 0; s < 18; ++s) {
        const int t = s >> 1;
        const int dy = t / 3, dx = t - dy * 3;
        const int aslot = (s & 1) * 4 + grp;
        half8 af[4];
#pragma unroll
        for (int mt = 0; mt < 4; ++mt) {
            int wrow = (mt + dy) * 18 + c + dx;
            af[mt] = *(const half8*)&xs[wrow * 64 + (aslot ^ (wrow & 7)) * 8];
        }
        const _Float16* wnext = wp + (size_t)(s + 1) * 4608;
#pragma unroll
        for (int k = 0; k < 9; ++k) {
            half8 cur = bf[k];
            // prefetch step s+1's fragment k (s=17: harmless overread into
            // the w1ws region, still inside the workspace; value unused)
            bf[k] = *(const half8*)(wnext + k * 512);
#pragma unroll
            for (int mt = 0; mt < 4; ++mt)
                acc[mt][k] = __builtin_amdgcn_mfma_f32_16x16x32_f16(
                    af[mt], cur, acc[mt][k], 0, 0, 0);
        }
    }

    // epilogue: lane-local softmax over 9 k per (pixel, ij)
    const int ij = wid * 16 + c;
    const int oi = ij >> 3, oj = ij & 7;
#pragma unroll
    for (int mt = 0; mt < 4; ++mt) {
#pragma unroll
        for (int r = 0; r < 4; ++r) {
            int pr = mt, pc = grp * 4 + r;
            float pat[9];
#pragma unroll
            for (int k9 = 0; k9 < 9; ++k9) pat[k9] = d8s[(pr + k9 / 3) * 18 + pc + k9 % 3];
            float mx = acc[mt][0][r];
#pragma unroll
            for (int k9 = 1; k9 < 9; ++k9) mx = fmaxf(mx, acc[mt][k9][r]);
            float sum = 0.f, up = 0.f;
#pragma unroll
            for (int k9 = 0; k9 < 9; ++k9) {
                float e = __expf(acc[mt][k9][r] - mx);
                sum += e; up += e * pat[k9];
            }
            int y = ty0 + pr, xc = tx0 + pc;
            out[((size_t)(b * (8 * H) + y * 8 + oi)) * (size_t)(8 * W) + xc * 8 + oj] = up / sum;
        }
    }
}

// ---------------------------------------------------------------------------
extern "C" void kernel_launch(void* const* d_in, const int* in_sizes, int n_in,
                              void* d_out, int out_size, void* d_ws, size_t ws_size,
                              hipStream_t stream)
{
    const float* guidance = (const float*)d_in[0];
    const float* disp     = (const float*)d_in[1];
    const float* conv1_w  = (const float*)d_in[2];
    const float* bn_gamma = (const float*)d_in[3];
    const float* bn_beta  = (const float*)d_in[4];
    const float* bn_mean  = (const float*)d_in[5];
    const float* bn_var   = (const float*)d_in[6];
    const float* conv2_w  = (const float*)d_in[7];
    float* out = (float*)d_out;
    char* ws = (char*)d_ws;
    _Float16* xg = (_Float16*)(ws + XG_OFF);

    prep<<<dim3((18 * 576 * 32 + 9 * 64 * 32 + 255) / 256), dim3(256), 0, stream>>>(
        conv1_w, conv2_w, ws);
    dim3 grid1(W / 8, H / 8, B_);    // (20, 10, 8)
    conv1_mfma<<<grid1, dim3(256), 0, stream>>>(
        guidance, ws + W1WS_OFF, bn_gamma, bn_beta, bn_mean, bn_var, xg);
    dim3 grid2(W / 16, H / 4, B_);   // (10, 20, 8)
    conv2_mfma<<<grid2, dim3(256), 0, stream>>>(
        xg, ws + CWS_OFF, disp, out);
}

// Round 8
// 120.096 us; speedup vs baseline: 1.2407x; 1.0408x over previous
//
#include <hip/hip_runtime.h>
#include <math.h>

typedef _Float16 half8 __attribute__((ext_vector_type(8)));
typedef float f32x4 __attribute__((ext_vector_type(4)));

// dims
constexpr int B_ = 8;
constexpr int HG = 160, WG = 320;          // guidance spatial
constexpr int H = 80, W = 160;             // x spatial
// ws layout (bytes)
constexpr size_t CWS_OFF  = 0;             // 4 ng * 165888 = 663552
constexpr size_t W1WS_OFF = 663552;        // 9 taps * 4096 = 36864
constexpr size_t XG_OFF   = 700416;        // 8*80*160*64*2 = 13107200

// ---------------------------------------------------------------------------
// prep: weight tensors -> MFMA B-operand register images (one thread per
// (n, cin), reading 9 contiguous taps).
// conv2: Cws [ng][18 s][9 k][1024B]; fragment byte layout: lane = grp*16+nl
//   (grp = kl>>3, nl = n&15) holds bytes [lane*16, lane*16+16) = kl j=grp*8..+8.
//   K = t*64 + cin -> s = 2t + (cin>>5), kl = cin&31. (identical to R7 layout)
// conv1: w1ws [t=9][nt 4][1024B]; same fragment image with kl = cin (32),
//   nl = ch&15, nt = ch>>4.
// ---------------------------------------------------------------------------
__global__ __launch_bounds__(256) void prep(const float* __restrict__ w1,
                                            const float* __restrict__ w2,
                                            char* __restrict__ ws)
{
    int e = blockIdx.x * 256 + threadIdx.x;
    if (e < 576 * 64) {
        int n = e >> 6, cin = e & 63;
        int k = n >> 6, ng = (n >> 4) & 3, nl = n & 15;
        int kl = cin & 31, c5 = cin >> 5;
        const float* src = w2 + ((size_t)(n * 64 + cin)) * 9;
        int fragoff = ((kl >> 3) * 16 + nl) * 16 + (kl & 7) * 2;
#pragma unroll
        for (int t = 0; t < 9; ++t) {
            int s = t * 2 + c5;
            *(_Float16*)(ws + CWS_OFF + (size_t)ng * 165888
                         + (size_t)(s * 9 + k) * 1024 + fragoff) = (_Float16)src[t];
        }
    } else if (e < 576 * 64 + 64 * 32) {
        int e2 = e - 576 * 64;
        int ch = e2 >> 5, cin = e2 & 31;
        const float* src = w1 + ((size_t)(ch * 32 + cin)) * 9;
        int fragoff = (ch >> 4) * 1024 + ((cin >> 3) * 16 + (ch & 15)) * 16 + (cin & 7) * 2;
#pragma unroll
        for (int t = 0; t < 9; ++t)
            *(_Float16*)(ws + W1WS_OFF + (size_t)t * 4096 + fragoff) = (_Float16)src[t];
    }
}

// ---------------------------------------------------------------------------
// conv1 (3x3 s2 p1, 32->64) + BN + ReLU via MFMA. Output f16 NHWC.
// NEW: 16x8 px tile, 4 waves (wave w: rows py = 2w, 2w+1; Mt=2, Nt=4),
// register-direct weights (no wlds, no K-loop barriers), guidance window in
// parity-split XOR-swizzled LDS [par][wr 17][wch 18][32cin] (2-way = free),
// float2 staging. acc[2][4]; 4 blocks/CU (157 KB LDS).
// ---------------------------------------------------------------------------
__global__ __launch_bounds__(256, 4) void conv1_mfma(
    const float* __restrict__ g, const char* __restrict__ ws_w1,
    const float* __restrict__ gamma, const float* __restrict__ beta,
    const float* __restrict__ mean, const float* __restrict__ var,
    _Float16* __restrict__ xg)
{
    const int tx0 = blockIdx.x * 16, ty0 = blockIdx.y * 8, b = blockIdx.z;
    __shared__ __align__(16) _Float16 gl[2][17][18][32];   // 39168 B
    const int tid = threadIdx.x;

    // stage guidance window: wc in [-?]: absolute gx = 2*tx0-1 + wc, wc 0..32.
    // float2 loads from even gxa = 2*tx0-2 + 2*c2; elem0 -> wc = 2*c2-1 (odd),
    // elem1 -> wc = 2*c2 (even). OOB -> 0 (zero padding).
    const int gy0 = 2 * ty0 - 1;
    const int gxa0 = 2 * tx0 - 2;
    for (int i = tid; i < 17 * 32 * 17; i += 256) {
        int wr = i / 544; int rem = i - wr * 544;
        int cin = rem / 17; int c2 = rem - cin * 17;
        int gy = gy0 + wr;
        int gxa = gxa0 + 2 * c2;
        float2 v = make_float2(0.f, 0.f);
        if (gy >= 0 && gy < HG && gxa >= 0)
            v = *(const float2*)(g + ((size_t)(b * 32 + cin) * HG + gy) * WG + gxa);
        int slot = cin >> 3, elem = cin & 7;
        if (c2 > 0) {
            int wch = c2 - 1;
            gl[1][wr][wch][((slot ^ ((wch >> 1) & 3)) << 3) + elem] = (_Float16)v.x;
        }
        {
            int wch = c2;
            gl[0][wr][wch][((slot ^ ((wch >> 1) & 3)) << 3) + elem] = (_Float16)v.y;
        }
    }

    const int lane = tid & 63, w = tid >> 6;
    const int c = lane & 15, grp = lane >> 4;

    const _Float16* w1p = (const _Float16*)ws_w1 + lane * 8;
    half8 bf[4];
#pragma unroll
    for (int nt = 0; nt < 4; ++nt) bf[nt] = *(const half8*)(w1p + nt * 512);

    f32x4 zf = {0.f, 0.f, 0.f, 0.f};
    f32x4 acc[2][4];
#pragma unroll
    for (int mt = 0; mt < 2; ++mt)
#pragma unroll
        for (int nt = 0; nt < 4; ++nt) acc[mt][nt] = zf;

    __syncthreads();   // gl ready; no further barriers

#pragma unroll
    for (int s = 0; s < 9; ++s) {
        const int dy = s / 3, dx = s - dy * 3;
        const int par = dx & 1, dxh = dx >> 1;
        half8 af[2];
#pragma unroll
        for (int mt = 0; mt < 2; ++mt) {
            int wr = 2 * (2 * w + mt) + dy;
            int wch = c + dxh;
            af[mt] = *(const half8*)&gl[par][wr][wch][(grp ^ ((wch >> 1) & 3)) << 3];
        }
        const _Float16* wnext = w1p + (size_t)(s + 1) * 2048;
#pragma unroll
        for (int nt = 0; nt < 4; ++nt) {
            half8 cur = bf[nt];
            // prefetch tap s+1 (s=8 overreads into xg region: harmless)
            bf[nt] = *(const half8*)(wnext + nt * 512);
            acc[0][nt] = __builtin_amdgcn_mfma_f32_16x16x32_f16(af[0], cur, acc[0][nt], 0, 0, 0);
            acc[1][nt] = __builtin_amdgcn_mfma_f32_16x16x32_f16(af[1], cur, acc[1][nt], 0, 0, 0);
        }
    }

    // epilogue: BN + ReLU + NHWC f16 store. C/D: col = lane&15 = ch-in-frag,
    // row = grp*4+r = px column xx; py = 2w+mt.
#pragma unroll
    for (int nt = 0; nt < 4; ++nt) {
        int ch = nt * 16 + c;
        float mu = mean[ch], scv = rsqrtf(var[ch] + 1e-5f) * gamma[ch], bt = beta[ch];
#pragma unroll
        for (int mt = 0; mt < 2; ++mt) {
            int y = ty0 + 2 * w + mt;
#pragma unroll
            for (int r = 0; r < 4; ++r) {
                int x = tx0 + grp * 4 + r;
                float v = fmaxf((acc[mt][nt][r] - mu) * scv + bt, 0.f);
                xg[(((size_t)(b * H + y) * W + x) << 6) + ch] = (_Float16)v;
            }
        }
    }
}

// ---------------------------------------------------------------------------
// conv2 (3x3 s1 p1, 64->576) + softmax(9) + convex combine + pixel shuffle.
// REGISTER-DIRECT B (R7 engine), now 128 px/block: 512 thr = 8 waves,
// ng = wid&3 (16-ij set, k-complete per lane -> lane-local softmax),
// mg = wid>>2 (px rows mg*4..mg*4+3). Halves total weight traffic vs 64-px
// blocks. No LDS for B, no K-loop barriers.
// ---------------------------------------------------------------------------
__global__ __launch_bounds__(512, 2) void conv2_mfma(
    const _Float16* __restrict__ xg, const char* __restrict__ ws_c,
    const float* __restrict__ disp, float* __restrict__ out)
{
    const int tx0 = blockIdx.x * 16, ty0 = blockIdx.y * 8, b = blockIdx.z;
    __shared__ __align__(16) _Float16 xs[180 * 64];   // 10r x 18c x 64ch, 23040 B
    __shared__ float d8s[180];
    const int tid = threadIdx.x;
    const int lane = tid & 63, wid = tid >> 6;

    // stage x window 10x18x64 f16, swizzled: 16B slot' = slot ^ (wp&7)
    half8 zero8;
#pragma unroll
    for (int j = 0; j < 8; ++j) zero8[j] = (_Float16)0.f;
    for (int cidx = tid; cidx < 1440; cidx += 512) {
        int wp = cidx >> 3, slot = cidx & 7;
        int rr = wp / 18, cc = wp - rr * 18;
        int y = ty0 - 1 + rr, xc = tx0 - 1 + cc;
        half8 v = zero8;
        if (y >= 0 && y < H && xc >= 0 && xc < W)
            v = *(const half8*)(xg + (((size_t)(b * H + y) * W + xc) << 6) + slot * 8);
        *(half8*)&xs[wp * 64 + (slot ^ (wp & 7)) * 8] = v;
    }
    if (tid < 180) {
        int rr = tid / 18, cc = tid - rr * 18;
        int y = ty0 - 1 + rr, xc = tx0 - 1 + cc;
        float v = 0.f;
        if (y >= 0 && y < H && xc >= 0 && xc < W) v = 8.f * disp[(b * H + y) * W + xc];
        d8s[tid] = v;
    }

    const int ng = wid & 3, mg = wid >> 2;
    const int c = lane & 15, grp = lane >> 4;

    f32x4 zf = {0.f, 0.f, 0.f, 0.f};
    f32x4 acc[4][9];
#pragma unroll
    for (int m = 0; m < 4; ++m)
#pragma unroll
        for (int k = 0; k < 9; ++k) acc[m][k] = zf;

    // this wave's weight stream: [18 s][9 k][1024B], lane slice = lane*16 B
    const _Float16* wp = (const _Float16*)ws_c + (size_t)ng * 82944 + lane * 8;

    half8 bf[9];
#pragma unroll
    for (int k = 0; k < 9; ++k) bf[k] = *(const half8*)(wp + k * 512);

    __syncthreads();   // xs, d8s ready

#pragma unroll 2
    for (int s = 0; s < 18; ++s) {
        const int t = s >> 1;
        const int dy = t / 3, dx = t - dy * 3;
        const int aslot = (s & 1) * 4 + grp;
        half8 af[4];
#pragma unroll
        for (int mt = 0; mt < 4; ++mt) {
            int wrow = (mg * 4 + mt + dy) * 18 + c + dx;
            af[mt] = *(const half8*)&xs[wrow * 64 + (aslot ^ (wrow & 7)) * 8];
        }
        const _Float16* wnext = wp + (size_t)(s + 1) * 4608;
#pragma unroll
        for (int k = 0; k < 9; ++k) {
            half8 cur = bf[k];
            // prefetch step s+1 fragment k (s=17 overreads into w1ws: harmless)
            bf[k] = *(const half8*)(wnext + k * 512);
#pragma unroll
            for (int mt = 0; mt < 4; ++mt)
                acc[mt][k] = __builtin_amdgcn_mfma_f32_16x16x32_f16(
                    af[mt], cur, acc[mt][k], 0, 0, 0);
        }
    }

    // epilogue: lane-local softmax over 9 k per (pixel, ij)
    const int ij = ng * 16 + c;
    const int oi = ij >> 3, oj = ij & 7;
#pragma unroll
    for (int mt = 0; mt < 4; ++mt) {
#pragma unroll
        for (int r = 0; r < 4; ++r) {
            int pr = mg * 4 + mt, pc = grp * 4 + r;
            float pat[9];
#pragma unroll
            for (int k9 = 0; k9 < 9; ++k9) pat[k9] = d8s[(pr + k9 / 3) * 18 + pc + k9 % 3];
            float mx = acc[mt][0][r];
#pragma unroll
            for (int k9 = 1; k9 < 9; ++k9) mx = fmaxf(mx, acc[mt][k9][r]);
            float sum = 0.f, up = 0.f;
#pragma unroll
            for (int k9 = 0; k9 < 9; ++k9) {
                float e = __expf(acc[mt][k9][r] - mx);
                sum += e; up += e * pat[k9];
            }
            int y = ty0 + pr, xc = tx0 + pc;
            out[((size_t)(b * (8 * H) + y * 8 + oi)) * (size_t)(8 * W) + xc * 8 + oj] = up / sum;
        }
    }
}

// ---------------------------------------------------------------------------
extern "C" void kernel_launch(void* const* d_in, const int* in_sizes, int n_in,
                              void* d_out, int out_size, void* d_ws, size_t ws_size,
                              hipStream_t stream)
{
    const float* guidance = (const float*)d_in[0];
    const float* disp     = (const float*)d_in[1];
    const float* conv1_w  = (const float*)d_in[2];
    const float* bn_gamma = (const float*)d_in[3];
    const float* bn_beta  = (const float*)d_in[4];
    const float* bn_mean  = (const float*)d_in[5];
    const float* bn_var   = (const float*)d_in[6];
    const float* conv2_w  = (const float*)d_in[7];
    float* out = (float*)d_out;
    char* ws = (char*)d_ws;
    _Float16* xg = (_Float16*)(ws + XG_OFF);

    prep<<<dim3((576 * 64 + 64 * 32 + 255) / 256), dim3(256), 0, stream>>>(
        conv1_w, conv2_w, ws);
    dim3 grid1(W / 16, H / 8, B_);   // (10, 10, 8)
    conv1_mfma<<<grid1, dim3(256), 0, stream>>>(
        guidance, ws + W1WS_OFF, bn_gamma, bn_beta, bn_mean, bn_var, xg);
    dim3 grid2(W / 16, H / 8, B_);   // (10, 10, 8)
    conv2_mfma<<<grid2, dim3(512), 0, stream>>>(
        xg, ws + CWS_OFF, disp, out);
}